// Round 18
// baseline (288.991 us; speedup 1.0000x reference)
//
#include <hip/hip_runtime.h>

// CRF forward via parallel-in-time segmented scan. B=256, T<=2048, C=64.
// q_t = diag(ex_t)·E·q_{t-1} (linear) => P=64 segments per batch (SEG=32).
// K1: DYNAMIC WORK QUEUE: 4096 persistent blocks (64 thr) pop (b,s) tasks
//     from a global atomic counter (16384 tasks, b-major); inactive tasks
//     (nsteps<=0) cost one cached load. Fixes the r15-r17 residency decay
//     (sorted lens -> static blocks drained early; occ stuck at 19%).
//     Step = r17-verbatim (proven): 32x mfma_f32_16x16x32_bf16 per step,
//     3-phase wide-ILP; kappa(g,i)=4g+(i&3)+16(i>>2) on BOTH A(=exp(trans))
//     and B -> lane-local recirculation via cvt_pk; er=exp2(x*L2E) staged in
//     LDS; renorm every 4 steps, exact bookkeeping Lseg -= log2(r).
// K2: one wave per batch: q <- renorm(M_s·q) over segments (proven 10-17).

#define CC 64

typedef short bf16x8 __attribute__((ext_vector_type(8)));
typedef float f32x4 __attribute__((ext_vector_type(4)));

union PackAB { int w[4]; bf16x8 v; };

__device__ __forceinline__ int cvtpk(float lo, float hi) {
    int r;
    asm("v_cvt_pk_bf16_f32 %0, %1, %2" : "=v"(r) : "v"(lo), "v"(hi));
    return r;
}
__device__ __forceinline__ float bcast0(float v) {
    return __int_as_float(__builtin_amdgcn_readfirstlane(__float_as_int(v)));
}

#define LDS_FENCE() asm volatile("s_waitcnt lgkmcnt(0)" ::: "memory")

// one matmul step: M_new = diag(er[*r_])·(E·M_old); M lives in Bf (bf16)
template <bool SCALE>
__device__ __forceinline__ void chain_step(const bf16x8 (&A)[4][2], PackAB (&Bf)[2][4],
                                           const f32x4* __restrict__ er4, int g,
                                           float r_, float& ns0) {
    f32x4 er[4];
    #pragma unroll
    for (int mt = 0; mt < 4; ++mt) {
        er[mt] = er4[4 * mt + g];                // ds_read_b128, broadcast/16
        if (SCALE) er[mt] *= r_;
    }

    // phase 1: 16 independent first-half MFMAs
    f32x4 D[4][4];                               // D[nt][mt], all static-indexed
    #pragma unroll
    for (int nt = 0; nt < 4; ++nt) {
        f32x4 Z = {0.f, 0.f, 0.f, 0.f};
        #pragma unroll
        for (int mt = 0; mt < 4; ++mt)
            D[nt][mt] = __builtin_amdgcn_mfma_f32_16x16x32_bf16(A[mt][0], Bf[0][nt].v, Z, 0, 0, 0);
    }
    // phase 2: 16 chained second-half MFMAs (accumulate into D)
    #pragma unroll
    for (int nt = 0; nt < 4; ++nt)
        #pragma unroll
        for (int mt = 0; mt < 4; ++mt)
            D[nt][mt] = __builtin_amdgcn_mfma_f32_16x16x32_bf16(A[mt][1], Bf[1][nt].v, D[nt][mt], 0, 0, 0);

    ns0 = D[0][0][0];                            // raw D[0][0], pre-scale

    // phase 3: scale + repack into Bf
    #pragma unroll
    for (int nt = 0; nt < 4; ++nt) {
        f32x4 d0 = D[nt][0] * er[0];
        f32x4 d1 = D[nt][1] * er[1];
        f32x4 d2 = D[nt][2] * er[2];
        f32x4 d3 = D[nt][3] * er[3];
        Bf[0][nt].w[0] = cvtpk(d0[0], d0[1]);
        Bf[0][nt].w[1] = cvtpk(d0[2], d0[3]);
        Bf[0][nt].w[2] = cvtpk(d1[0], d1[1]);
        Bf[0][nt].w[3] = cvtpk(d1[2], d1[3]);
        Bf[1][nt].w[0] = cvtpk(d2[0], d2[1]);
        Bf[1][nt].w[1] = cvtpk(d2[2], d2[3]);
        Bf[1][nt].w[2] = cvtpk(d3[0], d3[1]);
        Bf[1][nt].w[3] = cvtpk(d3[2], d3[3]);
    }
}

__launch_bounds__(64, 3)
__global__ void crf_seg_kernel(const float* __restrict__ x,      // (B,T,C)
                               const float* __restrict__ trans,  // (C,C)
                               const int*   __restrict__ lens,   // (B,)
                               unsigned short* __restrict__ Mws, // (B*P,64,64) bf16
                               float* __restrict__ Ls,           // (B*P,)
                               int* __restrict__ wq,             // work counter
                               int T, int Pseg, int SEG, int ntasks) {
    const int l = threadIdx.x;
    const int c = l & 15, g = l >> 4;
    const float L2E = 1.4426950408889634f;

    __shared__ float xl[32][CC];                  // 8 KiB: er rows of one segment

    // A frags (once): slot (g,i) = exp(trans[16mt+c][32ch + kappa(g,i)])
    bf16x8 A[4][2];
    #pragma unroll
    for (int mt = 0; mt < 4; ++mt) {
        const float* tr = trans + (16 * mt + c) * CC;
        #pragma unroll
        for (int ch = 0; ch < 2; ++ch) {
            float4 u = *(const float4*)(tr + 32 * ch + 4 * g);
            float4 v = *(const float4*)(tr + 32 * ch + 16 + 4 * g);
            PackAB pk;
            pk.w[0] = cvtpk(__builtin_amdgcn_exp2f(u.x * L2E), __builtin_amdgcn_exp2f(u.y * L2E));
            pk.w[1] = cvtpk(__builtin_amdgcn_exp2f(u.z * L2E), __builtin_amdgcn_exp2f(u.w * L2E));
            pk.w[2] = cvtpk(__builtin_amdgcn_exp2f(v.x * L2E), __builtin_amdgcn_exp2f(v.y * L2E));
            pk.w[3] = cvtpk(__builtin_amdgcn_exp2f(v.z * L2E), __builtin_amdgcn_exp2f(v.w * L2E));
            A[mt][ch] = pk.v;
        }
    }
    // identity template in fragment form (verified rounds 8/10-17)
    PackAB Bid[2][4];
    #pragma unroll
    for (int ch = 0; ch < 2; ++ch)
        #pragma unroll
        for (int nt = 0; nt < 4; ++nt)
            #pragma unroll
            for (int qq = 0; qq < 4; ++qq) {
                int i0 = 2 * qq, i1 = 2 * qq + 1;
                int k0 = 32 * ch + 4 * g + (i0 & 3) + 16 * (i0 >> 2);
                int k1 = 32 * ch + 4 * g + (i1 & 3) + 16 * (i1 >> 2);
                Bid[ch][nt].w[qq] = cvtpk((k0 == 16 * nt + c) ? 1.f : 0.f,
                                          (k1 == 16 * nt + c) ? 1.f : 0.f);
            }

    // dynamic work loop: pop (b,s) tasks until the queue drains
    while (true) {
        int t;
        if (l == 0) t = atomicAdd(wq, 1);
        t = __shfl(t, 0, 64);
        if (t >= ntasks) break;

        const int b = t >> 6;                     // Pseg == 64
        const int s = t & (Pseg - 1);
        const int L = lens[b];
        const int tbeg = s * SEG;
        int segend = (s + 1) * SEG; if (segend > L - 1) segend = L - 1;
        const int nsteps = segend - tbeg;
        if (nsteps <= 0) continue;                // inactive task: cheap skip

        const float* xb = x + (size_t)b * T * CC;

        // stage er = exp2(x*L2E) for rows tbeg+1..segend (clamped)
        {
            const int rl = l >> 4;                // row within 4-row group
            const int cl = (l & 15) * 4;          // col chunk
            LDS_FENCE();                          // prior task's reads done
            f32x4 st[8];
            #pragma unroll
            for (int i = 0; i < 8; ++i) {
                int tr = tbeg + 1 + 4 * i + rl;
                if (tr > segend) tr = segend;
                st[i] = *(const f32x4*)(xb + (size_t)tr * CC + cl);
            }
            #pragma unroll
            for (int i = 0; i < 8; ++i) {
                f32x4 e;
                #pragma unroll
                for (int r = 0; r < 4; ++r)
                    e[r] = __builtin_amdgcn_exp2f(st[i][r] * L2E);
                *(f32x4*)&xl[4 * i + rl][cl] = e;
            }
            LDS_FENCE();                          // single wave: lgkm drain
        }

        PackAB Bf[2][4];
        #pragma unroll
        for (int ch = 0; ch < 2; ++ch)
            #pragma unroll
            for (int nt = 0; nt < 4; ++nt) Bf[ch][nt] = Bid[ch][nt];

        float Lseg = 0.f, ns0 = 1.0f;
        for (int base = 0; base < nsteps; base += 4) {
            float r_ = 1.0f;
            if (base > 0) {                       // renorm once per 4 steps
                float S00 = bcast0(ns0);
                r_ = __builtin_amdgcn_rcpf(S00);
                Lseg -= __builtin_amdgcn_logf(r_);   // log2 of ACTUAL scale
            }
            chain_step<true >(A, Bf, (const f32x4*)&xl[base][0], g, r_, ns0);
            if (base + 1 < nsteps) chain_step<false>(A, Bf, (const f32x4*)&xl[base + 1][0], g, 1.f, ns0);
            if (base + 2 < nsteps) chain_step<false>(A, Bf, (const f32x4*)&xl[base + 2][0], g, 1.f, ns0);
            if (base + 3 < nsteps) chain_step<false>(A, Bf, (const f32x4*)&xl[base + 3][0], g, 1.f, ns0);
        }

        // store M_s as bf16 row-major [row][col] + Lseg
        unsigned short* Mo = Mws + (size_t)t * 4096;
        #pragma unroll
        for (int ch = 0; ch < 2; ++ch)
            #pragma unroll
            for (int nt = 0; nt < 4; ++nt)
                #pragma unroll
                for (int e = 0; e < 8; ++e) {
                    unsigned wb = (unsigned)Bf[ch][nt].w[e >> 1];
                    unsigned short hb = (e & 1) ? (unsigned short)(wb >> 16)
                                                : (unsigned short)(wb & 0xffffu);
                    int row = 32 * ch + 4 * g + (e & 3) + 16 * (e >> 2);
                    Mo[row * 64 + 16 * nt + c] = hb;
                }
        if (l == 0) Ls[t] = Lseg;
    }
}

__launch_bounds__(64, 1)
__global__ void crf_apply_kernel(const float* __restrict__ x,
                                 const float* __restrict__ orig,
                                 const int*   __restrict__ lens,
                                 const unsigned short* __restrict__ Mws,
                                 const float* __restrict__ Ls,
                                 float* __restrict__ out,
                                 int T, int Pseg, int SEG) {
    const int b = blockIdx.x, j = threadIdx.x;
    __shared__ float qb[CC];
    const float L2E = 1.4426950408889634f, LN2 = 0.6931471805599453f;
    const int L = lens[b];
    const float* xb = x + (size_t)b * T * CC;

    float Mbar = (xb[0] + orig[0]) * L2E;
    float q = __builtin_amdgcn_exp2f((xb[j] + orig[j]) * L2E - Mbar);

    // 1-deep prefetch of this lane's bf16 row (row j of M_s)
    uint4 R[8];
    {
        const uint4* Ms = (const uint4*)(Mws + ((size_t)b * Pseg + 0) * 4096 + j * 64);
        #pragma unroll
        for (int i = 0; i < 8; ++i) R[i] = Ms[i];
    }

    for (int s = 0; s < Pseg; ++s) {
        int tbeg = s * SEG;
        int segend = (s + 1) * SEG; if (segend > L - 1) segend = L - 1;
        if (segend - tbeg <= 0) break;   // later segments inactive too

        uint4 Rc[8];
        #pragma unroll
        for (int i = 0; i < 8; ++i) Rc[i] = R[i];
        {   // prefetch next segment's row (clamped; garbage unused if inactive)
            int s2 = (s + 1 < Pseg) ? s + 1 : s;
            const uint4* Ms = (const uint4*)(Mws + ((size_t)b * Pseg + s2) * 4096 + j * 64);
            #pragma unroll
            for (int i = 0; i < 8; ++i) R[i] = Ms[i];
        }

        qb[j] = q;
        LDS_FENCE();

        float acc = 0.f;
        #pragma unroll
        for (int i = 0; i < 8; ++i) {
            f32x4 qv0 = *(const f32x4*)&qb[8 * i];
            f32x4 qv1 = *(const f32x4*)&qb[8 * i + 4];
            unsigned u0 = Rc[i].x, u1 = Rc[i].y, u2 = Rc[i].z, u3 = Rc[i].w;
            acc = fmaf(__uint_as_float(u0 << 16),        qv0[0], acc);
            acc = fmaf(__uint_as_float(u0 & 0xffff0000), qv0[1], acc);
            acc = fmaf(__uint_as_float(u1 << 16),        qv0[2], acc);
            acc = fmaf(__uint_as_float(u1 & 0xffff0000), qv0[3], acc);
            acc = fmaf(__uint_as_float(u2 << 16),        qv1[0], acc);
            acc = fmaf(__uint_as_float(u2 & 0xffff0000), qv1[1], acc);
            acc = fmaf(__uint_as_float(u3 << 16),        qv1[2], acc);
            acc = fmaf(__uint_as_float(u3 & 0xffff0000), qv1[3], acc);
        }
        float S = acc;
        Mbar += Ls[(size_t)b * Pseg + s];
        float p = bcast0(S);
        float r = __builtin_amdgcn_rcpf(p);
        float lgr = __builtin_amdgcn_logf(r);
        q = S * r;
        Mbar -= lgr;
        LDS_FENCE();   // reads of qb done before next overwrite
    }

    float alpha = LN2 * (Mbar + __builtin_amdgcn_logf(q));
    alpha += __shfl_xor(alpha, 1, 64);
    alpha += __shfl_xor(alpha, 2, 64);
    alpha += __shfl_xor(alpha, 4, 64);
    alpha += __shfl_xor(alpha, 8, 64);
    alpha += __shfl_xor(alpha, 16, 64);
    alpha += __shfl_xor(alpha, 32, 64);
    if (j == 0) out[b] = alpha;
}

extern "C" void kernel_launch(void* const* d_in, const int* in_sizes, int n_in,
                              void* d_out, int out_size, void* d_ws, size_t ws_size,
                              hipStream_t stream) {
    const float* x     = (const float*)d_in[0];
    const float* trans = (const float*)d_in[1];
    const float* orig  = (const float*)d_in[2];
    const int*   lens  = (const int*)d_in[3];
    float* out = (float*)d_out;

    const int B = in_sizes[3];
    const int T = in_sizes[0] / (B * CC);

    const int P = 64;                             // 128.06 MB ws required
    const int SEG = (T + P - 1) / P;
    const int ntasks = B * P;

    unsigned short* Mws = (unsigned short*)d_ws;
    float* Ls = (float*)(Mws + (size_t)B * P * 4096);
    int* wq = (int*)(Ls + ntasks);

    hipMemsetAsync(wq, 0, sizeof(int), stream);   // reset queue (capturable)

    crf_seg_kernel<<<4096, 64, 0, stream>>>(x, trans, lens, Mws, Ls, wq,
                                            T, P, SEG, ntasks);
    crf_apply_kernel<<<B, 64, 0, stream>>>(x, orig, lens, Mws, Ls, out, T, P, SEG);
}

// Round 19
// 177.392 us; speedup vs baseline: 1.6291x; 1.6291x over previous
//
#include <hip/hip_runtime.h>

// CRF forward via parallel-in-time segmented scan. B=256, T<=2048, C=64.
// q_t = diag(ex_t)·E·q_{t-1} (linear) => P=64 segments per batch (SEG=32).
// K1: r17 structure (best: 193us) + T19 sched_group_barrier pin:
//     emission order forced to [4 ds_read][32 MFMA][VALU tail] per step —
//     the compiler's default schedule serializes each MFMA pair behind its
//     consumer muls (VGPR=84 across r15-r18 proves the D[4][4] live set was
//     never allocated). launch_bounds(64,2) raises the VGPR cap to 256.
//     Chain math proven rounds 10-17: 32x mfma_f32_16x16x32_bf16 per step;
//     kappa(g,i)=4g+(i&3)+16(i>>2) on BOTH A(=exp(trans)) and B -> lane-local
//     recirculation via cvt_pk; er=exp2(x*L2E) staged in LDS; renorm every
//     4 steps, exact bookkeeping Lseg -= log2(r).
// K2: one wave per batch: q <- renorm(M_s·q) over segments (proven 10-17).

#define CC 64

typedef short bf16x8 __attribute__((ext_vector_type(8)));
typedef float f32x4 __attribute__((ext_vector_type(4)));

union PackAB { int w[4]; bf16x8 v; };

__device__ __forceinline__ int cvtpk(float lo, float hi) {
    int r;
    asm("v_cvt_pk_bf16_f32 %0, %1, %2" : "=v"(r) : "v"(lo), "v"(hi));
    return r;
}
__device__ __forceinline__ float bcast0(float v) {
    return __int_as_float(__builtin_amdgcn_readfirstlane(__float_as_int(v)));
}

#define LDS_FENCE() asm volatile("s_waitcnt lgkmcnt(0)" ::: "memory")

// one matmul step: M_new = diag(er[*r_])·(E·M_old); M lives in Bf (bf16)
template <bool SCALE>
__device__ __forceinline__ void chain_step(const bf16x8 (&A)[4][2], PackAB (&Bf)[2][4],
                                           const f32x4* __restrict__ er4, int g,
                                           float r_, float& ns0) {
    f32x4 er[4];
    #pragma unroll
    for (int mt = 0; mt < 4; ++mt) {
        er[mt] = er4[4 * mt + g];                // ds_read_b128, broadcast/16
        if (SCALE) er[mt] *= r_;
    }

    // phase 1: 16 independent first-half MFMAs
    f32x4 D[4][4];                               // D[nt][mt], all static-indexed
    #pragma unroll
    for (int nt = 0; nt < 4; ++nt) {
        f32x4 Z = {0.f, 0.f, 0.f, 0.f};
        #pragma unroll
        for (int mt = 0; mt < 4; ++mt)
            D[nt][mt] = __builtin_amdgcn_mfma_f32_16x16x32_bf16(A[mt][0], Bf[0][nt].v, Z, 0, 0, 0);
    }
    // phase 2: 16 chained second-half MFMAs (accumulate into D)
    #pragma unroll
    for (int nt = 0; nt < 4; ++nt)
        #pragma unroll
        for (int mt = 0; mt < 4; ++mt)
            D[nt][mt] = __builtin_amdgcn_mfma_f32_16x16x32_bf16(A[mt][1], Bf[1][nt].v, D[nt][mt], 0, 0, 0);

    ns0 = D[0][0][0];                            // raw D[0][0], pre-scale

    // phase 3: scale + repack into Bf
    #pragma unroll
    for (int nt = 0; nt < 4; ++nt) {
        f32x4 d0 = D[nt][0] * er[0];
        f32x4 d1 = D[nt][1] * er[1];
        f32x4 d2 = D[nt][2] * er[2];
        f32x4 d3 = D[nt][3] * er[3];
        Bf[0][nt].w[0] = cvtpk(d0[0], d0[1]);
        Bf[0][nt].w[1] = cvtpk(d0[2], d0[3]);
        Bf[0][nt].w[2] = cvtpk(d1[0], d1[1]);
        Bf[0][nt].w[3] = cvtpk(d1[2], d1[3]);
        Bf[1][nt].w[0] = cvtpk(d2[0], d2[1]);
        Bf[1][nt].w[1] = cvtpk(d2[2], d2[3]);
        Bf[1][nt].w[2] = cvtpk(d3[0], d3[1]);
        Bf[1][nt].w[3] = cvtpk(d3[2], d3[3]);
    }

    // T19: pin the schedule — reads first, then the full MFMA cluster,
    // then the VALU tail. Masks: DS_READ=0x100, MFMA=0x8, VALU=0x2.
    __builtin_amdgcn_sched_group_barrier(0x100, 4, 0);
    __builtin_amdgcn_sched_group_barrier(0x008, 32, 0);
    __builtin_amdgcn_sched_group_barrier(0x002, 80, 0);
}

__launch_bounds__(64, 2)
__global__ void crf_seg_kernel(const float* __restrict__ x,      // (B,T,C)
                               const float* __restrict__ trans,  // (C,C)
                               const int*   __restrict__ lens,   // (B,)
                               unsigned short* __restrict__ Mws, // (B*P,64,64) bf16
                               float* __restrict__ Ls,           // (B*P,)
                               int T, int Pseg, int NBshift, int SEG) {
    const int blk = blockIdx.x;                   // grid = B * NB (NB=16)
    const int b = blk >> NBshift;
    const int j = blk & ((1 << NBshift) - 1);
    const int NB = 1 << NBshift;
    const int L = lens[b];

    const int l = threadIdx.x;
    const int c = l & 15, g = l >> 4;
    const float L2E = 1.4426950408889634f;
    const float* xb = x + (size_t)b * T * CC;

    __shared__ float xl[32][CC];                  // 8 KiB: er rows of one segment

    // A frags (once): slot (g,i) = exp(trans[16mt+c][32ch + kappa(g,i)])
    bf16x8 A[4][2];
    #pragma unroll
    for (int mt = 0; mt < 4; ++mt) {
        const float* tr = trans + (16 * mt + c) * CC;
        #pragma unroll
        for (int ch = 0; ch < 2; ++ch) {
            float4 u = *(const float4*)(tr + 32 * ch + 4 * g);
            float4 v = *(const float4*)(tr + 32 * ch + 16 + 4 * g);
            PackAB pk;
            pk.w[0] = cvtpk(__builtin_amdgcn_exp2f(u.x * L2E), __builtin_amdgcn_exp2f(u.y * L2E));
            pk.w[1] = cvtpk(__builtin_amdgcn_exp2f(u.z * L2E), __builtin_amdgcn_exp2f(u.w * L2E));
            pk.w[2] = cvtpk(__builtin_amdgcn_exp2f(v.x * L2E), __builtin_amdgcn_exp2f(v.y * L2E));
            pk.w[3] = cvtpk(__builtin_amdgcn_exp2f(v.z * L2E), __builtin_amdgcn_exp2f(v.w * L2E));
            A[mt][ch] = pk.v;
        }
    }
    // identity template in fragment form (verified rounds 8/10-17)
    PackAB Bid[2][4];
    #pragma unroll
    for (int ch = 0; ch < 2; ++ch)
        #pragma unroll
        for (int nt = 0; nt < 4; ++nt)
            #pragma unroll
            for (int qq = 0; qq < 4; ++qq) {
                int i0 = 2 * qq, i1 = 2 * qq + 1;
                int k0 = 32 * ch + 4 * g + (i0 & 3) + 16 * (i0 >> 2);
                int k1 = 32 * ch + 4 * g + (i1 & 3) + 16 * (i1 >> 2);
                Bid[ch][nt].w[qq] = cvtpk((k0 == 16 * nt + c) ? 1.f : 0.f,
                                          (k1 == 16 * nt + c) ? 1.f : 0.f);
            }

    // persistent loop over this block's segments: s = j, j+NB, j+2NB, ...
    for (int s = j; s < Pseg; s += NB) {
        const int tbeg = s * SEG;
        int segend = (s + 1) * SEG; if (segend > L - 1) segend = L - 1;
        const int nsteps = segend - tbeg;
        if (nsteps <= 0) break;                   // larger s ⇒ also dead

        // stage er = exp2(x*L2E) for rows tbeg+1..segend (clamped)
        {
            const int rl = l >> 4;                // row within 4-row group
            const int cl = (l & 15) * 4;          // col chunk
            LDS_FENCE();                          // prior segment's reads done
            f32x4 st[8];
            #pragma unroll
            for (int i = 0; i < 8; ++i) {
                int tr = tbeg + 1 + 4 * i + rl;
                if (tr > segend) tr = segend;
                st[i] = *(const f32x4*)(xb + (size_t)tr * CC + cl);
            }
            #pragma unroll
            for (int i = 0; i < 8; ++i) {
                f32x4 e;
                #pragma unroll
                for (int r = 0; r < 4; ++r)
                    e[r] = __builtin_amdgcn_exp2f(st[i][r] * L2E);
                *(f32x4*)&xl[4 * i + rl][cl] = e;
            }
            LDS_FENCE();                          // single wave: lgkm drain
        }

        PackAB Bf[2][4];
        #pragma unroll
        for (int ch = 0; ch < 2; ++ch)
            #pragma unroll
            for (int nt = 0; nt < 4; ++nt) Bf[ch][nt] = Bid[ch][nt];

        float Lseg = 0.f, ns0 = 1.0f;
        for (int base = 0; base < nsteps; base += 4) {
            float r_ = 1.0f;
            if (base > 0) {                       // renorm once per 4 steps
                float S00 = bcast0(ns0);
                r_ = __builtin_amdgcn_rcpf(S00);
                Lseg -= __builtin_amdgcn_logf(r_);   // log2 of ACTUAL scale
            }
            chain_step<true >(A, Bf, (const f32x4*)&xl[base][0], g, r_, ns0);
            if (base + 1 < nsteps) chain_step<false>(A, Bf, (const f32x4*)&xl[base + 1][0], g, 1.f, ns0);
            if (base + 2 < nsteps) chain_step<false>(A, Bf, (const f32x4*)&xl[base + 2][0], g, 1.f, ns0);
            if (base + 3 < nsteps) chain_step<false>(A, Bf, (const f32x4*)&xl[base + 3][0], g, 1.f, ns0);
        }

        // store M_s as bf16 row-major [row][col] + Lseg
        unsigned short* Mo = Mws + ((size_t)b * Pseg + s) * 4096;
        #pragma unroll
        for (int ch = 0; ch < 2; ++ch)
            #pragma unroll
            for (int nt = 0; nt < 4; ++nt)
                #pragma unroll
                for (int e = 0; e < 8; ++e) {
                    unsigned wb = (unsigned)Bf[ch][nt].w[e >> 1];
                    unsigned short hb = (e & 1) ? (unsigned short)(wb >> 16)
                                                : (unsigned short)(wb & 0xffffu);
                    int row = 32 * ch + 4 * g + (e & 3) + 16 * (e >> 2);
                    Mo[row * 64 + 16 * nt + c] = hb;
                }
        if (l == 0) Ls[(size_t)b * Pseg + s] = Lseg;
    }
}

__launch_bounds__(64, 1)
__global__ void crf_apply_kernel(const float* __restrict__ x,
                                 const float* __restrict__ orig,
                                 const int*   __restrict__ lens,
                                 const unsigned short* __restrict__ Mws,
                                 const float* __restrict__ Ls,
                                 float* __restrict__ out,
                                 int T, int Pseg, int SEG) {
    const int b = blockIdx.x, j = threadIdx.x;
    __shared__ float qb[CC];
    const float L2E = 1.4426950408889634f, LN2 = 0.6931471805599453f;
    const int L = lens[b];
    const float* xb = x + (size_t)b * T * CC;

    float Mbar = (xb[0] + orig[0]) * L2E;
    float q = __builtin_amdgcn_exp2f((xb[j] + orig[j]) * L2E - Mbar);

    // 1-deep prefetch of this lane's bf16 row (row j of M_s)
    uint4 R[8];
    {
        const uint4* Ms = (const uint4*)(Mws + ((size_t)b * Pseg + 0) * 4096 + j * 64);
        #pragma unroll
        for (int i = 0; i < 8; ++i) R[i] = Ms[i];
    }

    for (int s = 0; s < Pseg; ++s) {
        int tbeg = s * SEG;
        int segend = (s + 1) * SEG; if (segend > L - 1) segend = L - 1;
        if (segend - tbeg <= 0) break;   // later segments inactive too

        uint4 Rc[8];
        #pragma unroll
        for (int i = 0; i < 8; ++i) Rc[i] = R[i];
        {   // prefetch next segment's row (clamped; garbage unused if inactive)
            int s2 = (s + 1 < Pseg) ? s + 1 : s;
            const uint4* Ms = (const uint4*)(Mws + ((size_t)b * Pseg + s2) * 4096 + j * 64);
            #pragma unroll
            for (int i = 0; i < 8; ++i) R[i] = Ms[i];
        }

        qb[j] = q;
        LDS_FENCE();

        float acc = 0.f;
        #pragma unroll
        for (int i = 0; i < 8; ++i) {
            f32x4 qv0 = *(const f32x4*)&qb[8 * i];
            f32x4 qv1 = *(const f32x4*)&qb[8 * i + 4];
            unsigned u0 = Rc[i].x, u1 = Rc[i].y, u2 = Rc[i].z, u3 = Rc[i].w;
            acc = fmaf(__uint_as_float(u0 << 16),        qv0[0], acc);
            acc = fmaf(__uint_as_float(u0 & 0xffff0000), qv0[1], acc);
            acc = fmaf(__uint_as_float(u1 << 16),        qv0[2], acc);
            acc = fmaf(__uint_as_float(u1 & 0xffff0000), qv0[3], acc);
            acc = fmaf(__uint_as_float(u2 << 16),        qv1[0], acc);
            acc = fmaf(__uint_as_float(u2 & 0xffff0000), qv1[1], acc);
            acc = fmaf(__uint_as_float(u3 << 16),        qv1[2], acc);
            acc = fmaf(__uint_as_float(u3 & 0xffff0000), qv1[3], acc);
        }
        float S = acc;
        Mbar += Ls[(size_t)b * Pseg + s];
        float p = bcast0(S);
        float r = __builtin_amdgcn_rcpf(p);
        float lgr = __builtin_amdgcn_logf(r);
        q = S * r;
        Mbar -= lgr;
        LDS_FENCE();   // reads of qb done before next overwrite
    }

    float alpha = LN2 * (Mbar + __builtin_amdgcn_logf(q));
    alpha += __shfl_xor(alpha, 1, 64);
    alpha += __shfl_xor(alpha, 2, 64);
    alpha += __shfl_xor(alpha, 4, 64);
    alpha += __shfl_xor(alpha, 8, 64);
    alpha += __shfl_xor(alpha, 16, 64);
    alpha += __shfl_xor(alpha, 32, 64);
    if (j == 0) out[b] = alpha;
}

extern "C" void kernel_launch(void* const* d_in, const int* in_sizes, int n_in,
                              void* d_out, int out_size, void* d_ws, size_t ws_size,
                              hipStream_t stream) {
    const float* x     = (const float*)d_in[0];
    const float* trans = (const float*)d_in[1];
    const float* orig  = (const float*)d_in[2];
    const int*   lens  = (const int*)d_in[3];
    float* out = (float*)d_out;

    const int B = in_sizes[3];
    const int T = in_sizes[0] / (B * CC);

    int P = 64;
    while (P > 16 && ws_size < (size_t)B * P * (4096 * 2 + 4)) P >>= 1;
    const int SEG = (T + P - 1) / P;
    const int NBshift = 4;                         // 16 persistent blocks/batch

    unsigned short* Mws = (unsigned short*)d_ws;
    float* Ls = (float*)(Mws + (size_t)B * P * 4096);

    crf_seg_kernel<<<B * 16, 64, 0, stream>>>(x, trans, lens, Mws, Ls,
                                              T, P, NBshift, SEG);
    crf_apply_kernel<<<B, 64, 0, stream>>>(x, orig, lens, Mws, Ls, out, T, P, SEG);
}